// Round 6
// baseline (427.863 us; speedup 1.0000x reference)
//
#include <hip/hip_runtime.h>
#include <math.h>

// Problem constants (fixed by setup_inputs)
#define M_SEG 128
#define S_SEG 512
#define HD 512
#define NHEAD 8
#define DHEAD 64
#define NROWS (M_SEG * S_SEG)   // 65536
#define QKVLD 1536              // fused qkv row stride
#define GAMMA_F 0.96875f
#define SCALE_F 0.125f          // d^-0.5

typedef unsigned short u16;
typedef float f32x4 __attribute__((ext_vector_type(4)));
typedef __bf16 bf16x8 __attribute__((ext_vector_type(8)));
typedef unsigned short ushort8 __attribute__((ext_vector_type(8)));
typedef unsigned short ushort4v __attribute__((ext_vector_type(4)));

__device__ __forceinline__ u16 f2bf(float f) {
    union { float f; unsigned u; } x; x.f = f;
    unsigned r = x.u + 0x7FFFu + ((x.u >> 16) & 1u);   // RNE
    return (u16)(r >> 16);
}
__device__ __forceinline__ float bf2f(u16 v) {
    union { unsigned u; float f; } x; x.u = ((unsigned)v) << 16;
    return x.f;
}
__device__ __forceinline__ int swzn(int n) { return (n & 3) ^ ((n >> 2) & 3); }

// async global->LDS, 16B per lane; LDS dest = wave-uniform base + lane*16
__device__ __forceinline__ void gload16(const u16* g, u16* l) {
    __builtin_amdgcn_global_load_lds(
        (const __attribute__((address_space(1))) void*)g,
        (__attribute__((address_space(3))) void*)l, 16, 0, 0);
}

// ---------------------------------------------------------------------------
// fp32 -> bf16, 8 elems/thread
// ---------------------------------------------------------------------------
__global__ __launch_bounds__(256) void convert_bf16(const float* __restrict__ in,
                                                    u16* __restrict__ outp, int n8)
{
    int idx = blockIdx.x * 256 + threadIdx.x;
    if (idx >= n8) return;
    const float4 a = *reinterpret_cast<const float4*>(&in[(size_t)idx * 8]);
    const float4 b = *reinterpret_cast<const float4*>(&in[(size_t)idx * 8 + 4]);
    ushort8 o;
    o[0] = f2bf(a.x); o[1] = f2bf(a.y); o[2] = f2bf(a.z); o[3] = f2bf(a.w);
    o[4] = f2bf(b.x); o[5] = f2bf(b.y); o[6] = f2bf(b.z); o[7] = f2bf(b.w);
    *reinterpret_cast<ushort8*>(&outp[(size_t)idx * 8]) = o;
}

// 4 weights in one launch (blockIdx.y selects), each 512x512
__global__ __launch_bounds__(256) void convert_weights(const float* __restrict__ w0,
                                                       const float* __restrict__ w1,
                                                       const float* __restrict__ w2,
                                                       const float* __restrict__ w3,
                                                       u16* __restrict__ outp)
{
    const int which = blockIdx.y;
    const float* src = which == 0 ? w0 : which == 1 ? w1 : which == 2 ? w2 : w3;
    u16* dst = outp + (size_t)which * 262144;
    int idx = blockIdx.x * 256 + threadIdx.x;        // 32768 per weight
    const float4 a = *reinterpret_cast<const float4*>(&src[(size_t)idx * 8]);
    const float4 b = *reinterpret_cast<const float4*>(&src[(size_t)idx * 8 + 4]);
    ushort8 o;
    o[0] = f2bf(a.x); o[1] = f2bf(a.y); o[2] = f2bf(a.z); o[3] = f2bf(a.w);
    o[4] = f2bf(b.x); o[5] = f2bf(b.y); o[6] = f2bf(b.z); o[7] = f2bf(b.w);
    *reinterpret_cast<ushort8*>(&dst[(size_t)idx * 8]) = o;
}

// ---------------------------------------------------------------------------
// Phase-split 256x256 bf16 MFMA GEMM (NT), K=512, BK=32, 16 K-tiles.
// (unchanged from R5 except EPI path removed — QKV only)
// ---------------------------------------------------------------------------
__global__ __launch_bounds__(512, 1) void gemm8p(const u16* __restrict__ A, int lda,
                                                 const u16* __restrict__ B,
                                                 u16* __restrict__ Cv, int ldc, int ntile)
{
    __shared__ __align__(16) u16 sm[49152];
    const int t    = threadIdx.x;
    const int lane = t & 63;
    const int w    = t >> 6;
    const int wrow = w >> 2;
    const int wcol = w & 3;

    const int nwg  = gridDim.x;
    const int cpx  = nwg >> 3;
    const int bid  = blockIdx.x;
    const int sbid = (bid & 7) * cpx + (bid >> 3);
    const int mt = sbid / ntile, nt = sbid % ntile;
    const int rowBase = mt * 256, colBase = nt * 256;

    const int srow = t >> 2;
    const int sks  = (t & 3) ^ ((srow >> 1) & 3);
    const size_t gA0 = (size_t)(rowBase +       srow) * lda + sks * 8;
    const size_t gA1 = (size_t)(rowBase + 128 + srow) * lda + sks * 8;
    const size_t gB0 = (size_t)(colBase +       srow) * HD  + sks * 8;
    const size_t gB1 = (size_t)(colBase + 128 + srow) * HD  + sks * 8;

    f32x4 acc[8][4];
#pragma unroll
    for (int i = 0; i < 8; ++i)
#pragma unroll
        for (int j = 0; j < 4; ++j)
            acc[i][j] = (f32x4){0.f, 0.f, 0.f, 0.f};

#define STAGE_A(kt, buf)                                                     \
    do {                                                                     \
        gload16(&A[gA0 + (kt) * 32], &sm[(buf) * 16384 + t * 8]);            \
        gload16(&A[gA1 + (kt) * 32], &sm[(buf) * 16384 + 4096 + t * 8]);     \
    } while (0)
#define STAGE_B(kt, buf)                                                     \
    do {                                                                     \
        gload16(&B[gB0 + (kt) * 32], &sm[(buf) * 16384 + 8192 + t * 8]);     \
        gload16(&B[gB1 + (kt) * 32], &sm[(buf) * 16384 + 12288 + t * 8]);    \
    } while (0)

    STAGE_A(0, 0); STAGE_B(0, 0);
    STAGE_A(1, 1); STAGE_B(1, 1);

    const int frow = lane & 15;
    const int fkc  = lane >> 4;

#pragma unroll 1
    for (int kt = 0; kt < 16; ++kt) {
        const int buf = kt % 3;
        const int nbuf = (kt + 2) % 3;

        if (kt < 15) asm volatile("s_waitcnt vmcnt(4)" ::: "memory");
        else         asm volatile("s_waitcnt vmcnt(0)" ::: "memory");
        __builtin_amdgcn_s_barrier();
        __builtin_amdgcn_sched_barrier(0);

        if (kt < 14) STAGE_A(kt + 2, nbuf);
        const u16* Ab = &sm[buf * 16384];
        const u16* Bb = &sm[buf * 16384 + 8192];
        bf16x8 af[4], bfv[4];
#pragma unroll
        for (int mf = 0; mf < 4; ++mf) {
            const int r = wrow * 128 + mf * 16 + frow;
            af[mf] = *reinterpret_cast<const bf16x8*>(&Ab[r * 32 + ((fkc ^ ((r >> 1) & 3)) << 3)]);
        }
#pragma unroll
        for (int nn = 0; nn < 4; ++nn) {
            const int r = wcol * 64 + nn * 16 + frow;
            bfv[nn] = *reinterpret_cast<const bf16x8*>(&Bb[r * 32 + ((fkc ^ ((r >> 1) & 3)) << 3)]);
        }
        __builtin_amdgcn_s_setprio(1);
#pragma unroll
        for (int mf = 0; mf < 4; ++mf)
#pragma unroll
            for (int nn = 0; nn < 4; ++nn)
                acc[mf][nn] = __builtin_amdgcn_mfma_f32_16x16x32_bf16(af[mf], bfv[nn], acc[mf][nn], 0, 0, 0);
        __builtin_amdgcn_s_setprio(0);

        if (kt < 14) STAGE_B(kt + 2, nbuf);
#pragma unroll
        for (int mf = 0; mf < 4; ++mf) {
            const int r = wrow * 128 + 64 + mf * 16 + frow;
            af[mf] = *reinterpret_cast<const bf16x8*>(&Ab[r * 32 + ((fkc ^ ((r >> 1) & 3)) << 3)]);
        }
        __builtin_amdgcn_s_setprio(1);
#pragma unroll
        for (int mf = 0; mf < 4; ++mf)
#pragma unroll
            for (int nn = 0; nn < 4; ++nn)
                acc[4 + mf][nn] = __builtin_amdgcn_mfma_f32_16x16x32_bf16(af[mf], bfv[nn], acc[4 + mf][nn], 0, 0, 0);
        __builtin_amdgcn_s_setprio(0);
    }
#undef STAGE_A
#undef STAGE_B

    const int orow = (lane >> 4) * 4;
    u16* ldsC = sm;
#pragma unroll
    for (int hp = 0; hp < 2; ++hp) {
        __syncthreads();
        if (wrow == hp) {
#pragma unroll
            for (int mm = 0; mm < 8; ++mm)
#pragma unroll
                for (int nn = 0; nn < 4; ++nn) {
                    const int row0 = mm * 16 + orow;
                    const int col  = wcol * 64 + nn * 16 + frow;
#pragma unroll
                    for (int r = 0; r < 4; ++r)
                        ldsC[(row0 + r) * 256 + col] = f2bf(acc[mm][nn][r]);
                }
        }
        __syncthreads();
#pragma unroll
        for (int p = 0; p < 8; ++p) {
            const int lin = p * 512 + t;
            const int row = lin >> 5, c8 = lin & 31;
            *reinterpret_cast<ushort8*>(
                &Cv[(size_t)(rowBase + hp * 128 + row) * ldc + colBase + c8 * 8]) =
                *reinterpret_cast<const ushort8*>(&ldsC[row * 256 + c8 * 8]);
        }
    }
}

// ---------------------------------------------------------------------------
// MFMA KtV: A[m,h,d,e] = sum_s k[m,s,d] * v[m,s,e].
// Per (h,m) block, 256 thr / 4 waves. 32-s chunks reg-staged and TRANSPOSED
// into LDS as [d][s] / [e][s] (XOR-swizzled: u16addr(d,s) = d*32 +
// (((s>>3)^((d>>1)&3))<<3) + (s&7); 2-way banks on write AND b128 read).
// Wave w computes e-cols [w*16, w*16+16), all 64 d-rows (4 m-frags).
// Raw lgkmcnt-only barriers keep the next chunk's global loads in flight.
// ---------------------------------------------------------------------------
__global__ __launch_bounds__(256) void kv_outer_mfma(const u16* __restrict__ qkv,
                                                     float* __restrict__ Abuf)
{
    __shared__ __align__(16) u16 kT[2048];
    __shared__ __align__(16) u16 vT[2048];
    const int t    = threadIdx.x;
    const int lane = t & 63;
    const int w    = t >> 6;
    const int hh   = blockIdx.x;
    const int m    = blockIdx.y;
    const int sl   = t & 31;            // s within chunk
    const int dg   = (t >> 5) * 8;      // d-group base
    const int frow = lane & 15, fkc = lane >> 4, orow = (lane >> 4) * 4;
    const size_t gbase = (size_t)(m * S_SEG) * QKVLD + 512 + hh * DHEAD + dg;

    f32x4 acc[4];
#pragma unroll
    for (int i = 0; i < 4; ++i) acc[i] = (f32x4){0.f, 0.f, 0.f, 0.f};

    ushort8 ka, va, kb, vb;

#define LOADC(c, K8, V8)                                                      \
    do {                                                                      \
        size_t g_ = gbase + (size_t)((c) * 32 + sl) * QKVLD;                  \
        K8 = *reinterpret_cast<const ushort8*>(&qkv[g_]);                     \
        V8 = *reinterpret_cast<const ushort8*>(&qkv[g_ + 512]);               \
    } while (0)
#define WRTC(K8, V8)                                                          \
    do {                                                                      \
        _Pragma("unroll")                                                     \
        for (int j = 0; j < 8; ++j) {                                         \
            const int d_ = dg + j;                                            \
            const int a_ = d_ * 32 + ((((sl >> 3) ^ ((d_ >> 1) & 3))) << 3) + (sl & 7); \
            kT[a_] = K8[j];                                                   \
            vT[a_] = V8[j];                                                   \
        }                                                                     \
    } while (0)
#define CMPC()                                                                \
    do {                                                                      \
        bf16x8 kf[4], vf;                                                     \
        _Pragma("unroll")                                                     \
        for (int mf = 0; mf < 4; ++mf) {                                      \
            const int d_ = mf * 16 + frow;                                    \
            kf[mf] = *reinterpret_cast<const bf16x8*>(                        \
                &kT[d_ * 32 + ((fkc ^ ((d_ >> 1) & 3)) << 3)]);               \
        }                                                                     \
        const int e_ = w * 16 + frow;                                         \
        vf = *reinterpret_cast<const bf16x8*>(                                \
            &vT[e_ * 32 + ((fkc ^ ((e_ >> 1) & 3)) << 3)]);                   \
        _Pragma("unroll")                                                     \
        for (int mf = 0; mf < 4; ++mf)                                        \
            acc[mf] = __builtin_amdgcn_mfma_f32_16x16x32_bf16(kf[mf], vf, acc[mf], 0, 0, 0); \
    } while (0)

    LOADC(0, ka, va);
#pragma unroll 1
    for (int cc = 0; cc < 16; cc += 2) {
        WRTC(ka, va);
        LOADC(cc + 1, kb, vb);
        asm volatile("s_waitcnt lgkmcnt(0)" ::: "memory");
        __builtin_amdgcn_s_barrier();
        __builtin_amdgcn_sched_barrier(0);
        CMPC();
        __builtin_amdgcn_s_barrier();

        WRTC(kb, vb);
        if (cc + 2 < 16) LOADC(cc + 2, ka, va);
        asm volatile("s_waitcnt lgkmcnt(0)" ::: "memory");
        __builtin_amdgcn_s_barrier();
        __builtin_amdgcn_sched_barrier(0);
        CMPC();
        __builtin_amdgcn_s_barrier();
    }
#undef LOADC
#undef WRTC
#undef CMPC

    const size_t hb = (size_t)(m * NHEAD + hh) * DHEAD * DHEAD;
#pragma unroll
    for (int mf = 0; mf < 4; ++mf)
#pragma unroll
        for (int r = 0; r < 4; ++r)
            Abuf[hb + (size_t)(mf * 16 + orow + r) * DHEAD + w * 16 + frow] = acc[mf][r];
}

// ---------------------------------------------------------------------------
// r_m = A_m + decay*r_{m-1} ;  Bc_m = scale*A_m + gamma^{m+1} * r_m  (fp32)
// ---------------------------------------------------------------------------
__global__ __launch_bounds__(256) void scan_kernel(const float* __restrict__ Abuf,
                                                   float* __restrict__ Bc)
{
    const int tid = blockIdx.x * 256 + threadIdx.x;   // 0..32767
    const float decay = powf(GAMMA_F, (float)S_SEG);
    float r = 0.0f;
    float g = 1.0f;
    for (int m = 0; m < M_SEG; ++m) {
        float a = Abuf[(size_t)m * 32768 + tid];
        r = fmaf(decay, r, a);
        g *= GAMMA_F;
        Bc[(size_t)m * 32768 + tid] = fmaf(g, r, SCALE_F * a);
    }
}

// ---------------------------------------------------------------------------
// FUSED: h = relu(q @ Bc) (kept in 128KB LDS, XOR-swizzled), then
// res = h @ Wo^T + msg + bias -> bf16 into resB (qkv k-slot, stride 1536).
// Block = 128 rows x 512 cols; 512 thr / 8 waves; LDS 160KB exactly.
// Phase 2: B reg-prefetch -> swizzled ds_write (T14 split), lgkmcnt-only
// barriers so B-loads stay in flight under MFMA.
// ---------------------------------------------------------------------------
__global__ __launch_bounds__(512, 1) void fuse_ho(const u16* __restrict__ qkv,
                                                  const float* __restrict__ Bc,
                                                  const u16* __restrict__ WoB,
                                                  const u16* __restrict__ msgb,
                                                  const float* __restrict__ bias,
                                                  u16* __restrict__ resB)
{
    __shared__ __align__(16) u16 smem[81920];   // 160 KiB: h[0:65536] + sh[65536:81920]
    u16* hL  = smem;
    u16* shU = smem + 65536;
    const int t    = threadIdx.x;
    const int lane = t & 63;
    const int w    = t >> 6;
    const int frow = lane & 15, fkc = lane >> 4, orow = (lane >> 4) * 4;
    const int rowBase = blockIdx.x * 128;
    const int m = rowBase >> 9;

    // ---------------- phase 1: h tiles per head ----------------
    for (int hh = 0; hh < NHEAD; ++hh) {
        __syncthreads();
        // stage BT[e][d] bf16 (pad 72) from Bc[m,hh]
#pragma unroll
        for (int i = 0; i < 2; ++i) {
            const int idx = t + i * 512;             // 1024 float4s
            const int d = idx >> 4, e4 = idx & 15;
            float4 v = *reinterpret_cast<const float4*>(
                &Bc[((size_t)(m * NHEAD + hh) * DHEAD + d) * DHEAD + e4 * 4]);
            shU[(e4 * 4 + 0) * 72 + d] = f2bf(v.x);
            shU[(e4 * 4 + 1) * 72 + d] = f2bf(v.y);
            shU[(e4 * 4 + 2) * 72 + d] = f2bf(v.z);
            shU[(e4 * 4 + 3) * 72 + d] = f2bf(v.w);
        }
        __syncthreads();

        f32x4 a1[4];
#pragma unroll
        for (int i = 0; i < 4; ++i) a1[i] = (f32x4){0.f, 0.f, 0.f, 0.f};
        bf16x8 qf[2];
#pragma unroll
        for (int ks = 0; ks < 2; ++ks)
            qf[ks] = *reinterpret_cast<const bf16x8*>(
                &qkv[(size_t)(rowBase + w * 16 + frow) * QKVLD + hh * DHEAD + ks * 32 + fkc * 8]);
#pragma unroll
        for (int ks = 0; ks < 2; ++ks)
#pragma unroll
            for (int nn = 0; nn < 4; ++nn) {
                bf16x8 bfr = *reinterpret_cast<const bf16x8*>(
                    &shU[(nn * 16 + frow) * 72 + ks * 32 + fkc * 8]);
                a1[nn] = __builtin_amdgcn_mfma_f32_16x16x32_bf16(qf[ks], bfr, a1[nn], 0, 0, 0);
            }
        // write h (swizzled scalar u16)
#pragma unroll
        for (int nn = 0; nn < 4; ++nn)
#pragma unroll
            for (int r = 0; r < 4; ++r) {
                const int row = w * 16 + orow + r;
                const int col = hh * DHEAD + nn * 16 + frow;
                hL[row * 512 + (col ^ ((row & 7) << 3))] = f2bf(fmaxf(a1[nn][r], 0.f));
            }
    }
    __syncthreads();

    // ---------------- phase 2: res = h @ Wo^T + msg + bias ----------------
    f32x4 acc[8][4];
#pragma unroll
    for (int i = 0; i < 8; ++i)
#pragma unroll
        for (int j = 0; j < 4; ++j)
            acc[i][j] = (f32x4){0.f, 0.f, 0.f, 0.f};

    ushort8 ra[4], rb[4];
#define LOADW(kt, rr)                                                         \
    do {                                                                      \
        _Pragma("unroll")                                                     \
        for (int c = 0; c < 4; ++c)                                           \
            rr[c] = *reinterpret_cast<const ushort8*>(                        \
                &WoB[(size_t)t * 512 + (kt) * 32 + c * 8]);                   \
    } while (0)
#define WRTW(rr)                                                              \
    do {                                                                      \
        _Pragma("unroll")                                                     \
        for (int c = 0; c < 4; ++c)                                           \
            *reinterpret_cast<ushort8*>(&shU[t * 32 + ((c ^ swzn(t)) << 3)]) = rr[c]; \
    } while (0)
#define CMPW(kt)                                                              \
    do {                                                                      \
        bf16x8 bf[4];                                                         \
        _Pragma("unroll")                                                     \
        for (int nn = 0; nn < 4; ++nn) {                                      \
            const int n2 = w * 64 + nn * 16 + frow;                           \
            bf[nn] = *reinterpret_cast<const bf16x8*>(                        \
                &shU[n2 * 32 + ((fkc ^ swzn(n2)) << 3)]);                     \
        }                                                                     \
        _Pragma("unroll")                                                     \
        for (int mm = 0; mm < 8; ++mm) {                                      \
            const int row = mm * 16 + frow;                                   \
            bf16x8 af = *reinterpret_cast<const bf16x8*>(                     \
                &hL[row * 512 + (((kt) * 32 + fkc * 8) ^ ((row & 7) << 3))]); \
            _Pragma("unroll")                                                 \
            for (int nn = 0; nn < 4; ++nn)                                    \
                acc[mm][nn] = __builtin_amdgcn_mfma_f32_16x16x32_bf16(af, bf[nn], acc[mm][nn], 0, 0, 0); \
        }                                                                     \
    } while (0)

    LOADW(0, ra);
#pragma unroll 1
    for (int kt = 0; kt < 16; kt += 2) {
        WRTW(ra);
        LOADW(kt + 1, rb);
        asm volatile("s_waitcnt lgkmcnt(0)" ::: "memory");
        __builtin_amdgcn_s_barrier();
        __builtin_amdgcn_sched_barrier(0);
        __builtin_amdgcn_s_setprio(1);
        CMPW(kt);
        __builtin_amdgcn_s_setprio(0);
        __builtin_amdgcn_s_barrier();

        WRTW(rb);
        if (kt + 2 < 16) LOADW(kt + 2, ra);
        asm volatile("s_waitcnt lgkmcnt(0)" ::: "memory");
        __builtin_amdgcn_s_barrier();
        __builtin_amdgcn_sched_barrier(0);
        __builtin_amdgcn_s_setprio(1);
        CMPW(kt + 1);
        __builtin_amdgcn_s_setprio(0);
        __builtin_amdgcn_s_barrier();
    }
#undef LOADW
#undef WRTW
#undef CMPW

    // epilogue: 8 passes of 16 rows through 32KB fp32 LDS, fused +msg+bias
    float* ldsF = (float*)shU;
#pragma unroll 1
    for (int p = 0; p < 8; ++p) {
        __syncthreads();
#pragma unroll
        for (int nn = 0; nn < 4; ++nn)
#pragma unroll
            for (int r = 0; r < 4; ++r)
                ldsF[(orow + r) * 512 + w * 64 + nn * 16 + frow] = acc[p][nn][r];
        __syncthreads();
#pragma unroll
        for (int i = 0; i < 4; ++i) {
            const int lin = i * 512 + t;          // 2048 f4-chunks: 16 rows x 128
            const int row = lin >> 7, c4 = lin & 127;
            const int grow = rowBase + p * 16 + row;
            float4 a = *reinterpret_cast<const float4*>(&ldsF[row * 512 + c4 * 4]);
            ushort4v x = *reinterpret_cast<const ushort4v*>(&msgb[(size_t)grow * HD + c4 * 4]);
            float4 b = *reinterpret_cast<const float4*>(&bias[c4 * 4]);
            ushort4v o;
            o[0] = f2bf(a.x + bf2f(x[0]) + b.x);
            o[1] = f2bf(a.y + bf2f(x[1]) + b.y);
            o[2] = f2bf(a.z + bf2f(x[2]) + b.z);
            o[3] = f2bf(a.w + bf2f(x[3]) + b.w);
            *reinterpret_cast<ushort4v*>(&resB[(size_t)grow * QKVLD + c4 * 4]) = o;
        }
    }
}

// ---------------------------------------------------------------------------
// GroupNorm from bf16 res (qkv k-slot, stride 1536) -> fp32 d_out rows 1..N
// ---------------------------------------------------------------------------
__global__ __launch_bounds__(256) void groupnorm_bf16(const u16* __restrict__ res,
                                                      float* __restrict__ out,
                                                      const float* __restrict__ gn_w,
                                                      const float* __restrict__ gn_b)
{
    const int g = blockIdx.x;
    const int m = blockIdx.y;
    const int t = threadIdx.x;
    const u16* base = res + (size_t)(m * S_SEG) * QKVLD + g * DHEAD;

    float sum = 0.0f, sq = 0.0f;
    for (int idx = t; idx < 4096; idx += 256) {      // 512 rows x 8 ushort8
        int s = idx >> 3, c8 = idx & 7;
        ushort8 v = *reinterpret_cast<const ushort8*>(&base[(size_t)s * QKVLD + c8 * 8]);
#pragma unroll
        for (int j = 0; j < 8; ++j) {
            float f = bf2f(v[j]);
            sum += f; sq += f * f;
        }
    }
    __shared__ float rs[256], rq[256];
    rs[t] = sum; rq[t] = sq;
    __syncthreads();
    for (int off = 128; off > 0; off >>= 1) {
        if (t < off) { rs[t] += rs[t + off]; rq[t] += rq[t + off]; }
        __syncthreads();
    }
    __shared__ float smean, sinv;
    if (t == 0) {
        float mean = rs[0] * (1.0f / 32768.0f);
        float var  = rq[0] * (1.0f / 32768.0f) - mean * mean;
        smean = mean;
        sinv  = rsqrtf(var + 1e-5f);
    }
    __syncthreads();
    const float mean = smean, inv = sinv;

    for (int idx = t; idx < 4096; idx += 256) {
        int s = idx >> 3, c8 = idx & 7;
        ushort8 v = *reinterpret_cast<const ushort8*>(&base[(size_t)s * QKVLD + c8 * 8]);
        float o[8];
#pragma unroll
        for (int j = 0; j < 8; ++j) {
            float wj = gn_w[g * DHEAD + c8 * 8 + j];
            float bj = gn_b[g * DHEAD + c8 * 8 + j];
            o[j] = (bf2f(v[j]) - mean) * inv * wj + bj;
        }
        float* dst = &out[(size_t)(1 + m * S_SEG + s) * HD + g * DHEAD + c8 * 8];
        *reinterpret_cast<float4*>(dst)     = make_float4(o[0], o[1], o[2], o[3]);
        *reinterpret_cast<float4*>(dst + 4) = make_float4(o[4], o[5], o[6], o[7]);
    }
}

__global__ void zero_row(float* __restrict__ out)
{
    int i = blockIdx.x * 256 + threadIdx.x;
    if (i < HD) out[i] = 0.0f;
}

// ---------------------------------------------------------------------------
extern "C" void kernel_launch(void* const* d_in, const int* in_sizes, int n_in,
                              void* d_out, int out_size, void* d_ws, size_t ws_size,
                              hipStream_t stream)
{
    const float* msg = (const float*)d_in[0];
    const float* Wq  = (const float*)d_in[1];
    const float* Wk  = (const float*)d_in[2];
    const float* Wv  = (const float*)d_in[3];
    const float* Wo  = (const float*)d_in[4];
    const float* bo  = (const float*)d_in[5];
    const float* gnw = (const float*)d_in[6];
    const float* gnb = (const float*)d_in[7];
    float* out = (float*)d_out;

    // d_out scratch (consumed before groupnorm rewrites d_out):
    //   msgb bf16 (67.1 MB) | Abuf fp32 (16.8 MB) | Bc fp32 (16.8 MB)
    u16*   msgb = (u16*)out;
    float* Abuf = out + 16777216;
    float* Bc   = out + 16777216 + 4194304;

    // d_ws: Wb 2 MB (Wq|Wk|Wv|Wo bf16) + qkv 201.3 MB (65536 x 1536).
    // fuse_ho writes bf16 res into qkv's k-slot (dead after kv_outer_mfma).
    u16* Wb   = (u16*)d_ws;
    u16* qkv  = Wb + 4 * 262144;
    u16* resB = qkv + 512;    // res bf16, stride 1536

    convert_weights<<<dim3(128, 4), 256, 0, stream>>>(Wq, Wk, Wv, Wo, Wb);
    convert_bf16<<<16384, 256, 0, stream>>>(msg, msgb, 4194304);

    // fused QKV GEMM: A=msgb (65536x512), B=[Wq;Wk;Wv] (1536x512) -> qkv
    gemm8p<<<1536, 512, 0, stream>>>(msgb, HD, Wb, qkv, QKVLD, 6);

    kv_outer_mfma<<<dim3(NHEAD, M_SEG), 256, 0, stream>>>(qkv, Abuf);
    scan_kernel<<<128, 256, 0, stream>>>(Abuf, Bc);

    // fused h + output GEMM + residual -> resB
    fuse_ho<<<512, 512, 0, stream>>>(qkv, Bc, Wb + 3 * 262144, msgb, bo, resB);

    zero_row<<<2, 256, 0, stream>>>(out);
    groupnorm_bf16<<<dim3(8, M_SEG), 256, 0, stream>>>(resB, out, gnw, gnb);
}

// Round 7
// 367.193 us; speedup vs baseline: 1.1652x; 1.1652x over previous
//
#include <hip/hip_runtime.h>
#include <math.h>

// Problem constants (fixed by setup_inputs)
#define M_SEG 128
#define S_SEG 512
#define HD 512
#define NHEAD 8
#define DHEAD 64
#define NROWS (M_SEG * S_SEG)   // 65536
#define QKVLD 1536              // fused qkv row stride
#define GAMMA_F 0.96875f
#define SCALE_F 0.125f          // d^-0.5

typedef unsigned short u16;
typedef float f32x4 __attribute__((ext_vector_type(4)));
typedef __bf16 bf16x8 __attribute__((ext_vector_type(8)));
typedef unsigned short ushort8 __attribute__((ext_vector_type(8)));
typedef unsigned short ushort4v __attribute__((ext_vector_type(4)));

__device__ __forceinline__ u16 f2bf(float f) {
    union { float f; unsigned u; } x; x.f = f;
    unsigned r = x.u + 0x7FFFu + ((x.u >> 16) & 1u);   // RNE
    return (u16)(r >> 16);
}
__device__ __forceinline__ float bf2f(u16 v) {
    union { unsigned u; float f; } x; x.u = ((unsigned)v) << 16;
    return x.f;
}

// async global->LDS, 16B per lane; LDS dest = wave-uniform base + lane*16
__device__ __forceinline__ void gload16(const u16* g, u16* l) {
    __builtin_amdgcn_global_load_lds(
        (const __attribute__((address_space(1))) void*)g,
        (__attribute__((address_space(3))) void*)l, 16, 0, 0);
}

// ---------------------------------------------------------------------------
// fp32 -> bf16, 8 elems/thread
// ---------------------------------------------------------------------------
__global__ __launch_bounds__(256) void convert_bf16(const float* __restrict__ in,
                                                    u16* __restrict__ outp, int n8)
{
    int idx = blockIdx.x * 256 + threadIdx.x;
    if (idx >= n8) return;
    const float4 a = *reinterpret_cast<const float4*>(&in[(size_t)idx * 8]);
    const float4 b = *reinterpret_cast<const float4*>(&in[(size_t)idx * 8 + 4]);
    ushort8 o;
    o[0] = f2bf(a.x); o[1] = f2bf(a.y); o[2] = f2bf(a.z); o[3] = f2bf(a.w);
    o[4] = f2bf(b.x); o[5] = f2bf(b.y); o[6] = f2bf(b.z); o[7] = f2bf(b.w);
    *reinterpret_cast<ushort8*>(&outp[(size_t)idx * 8]) = o;
}

// 4 weights in one launch (blockIdx.y selects), each 512x512
__global__ __launch_bounds__(256) void convert_weights(const float* __restrict__ w0,
                                                       const float* __restrict__ w1,
                                                       const float* __restrict__ w2,
                                                       const float* __restrict__ w3,
                                                       u16* __restrict__ outp)
{
    const int which = blockIdx.y;
    const float* src = which == 0 ? w0 : which == 1 ? w1 : which == 2 ? w2 : w3;
    u16* dst = outp + (size_t)which * 262144;
    int idx = blockIdx.x * 256 + threadIdx.x;        // 32768 per weight
    const float4 a = *reinterpret_cast<const float4*>(&src[(size_t)idx * 8]);
    const float4 b = *reinterpret_cast<const float4*>(&src[(size_t)idx * 8 + 4]);
    ushort8 o;
    o[0] = f2bf(a.x); o[1] = f2bf(a.y); o[2] = f2bf(a.z); o[3] = f2bf(a.w);
    o[4] = f2bf(b.x); o[5] = f2bf(b.y); o[6] = f2bf(b.z); o[7] = f2bf(b.w);
    *reinterpret_cast<ushort8*>(&dst[(size_t)idx * 8]) = o;
}

// ---------------------------------------------------------------------------
// 8-phase 256x256 bf16 MFMA GEMM (NT), K=512. m201-template port.
// BK=64, 8 K-tiles, 2 K-tiles per iteration (buf0=even, buf1=odd), 4 iters.
// LDS: 2 bufs x {A 256x64, B 256x64} bf16 = 128 KiB. Half-tiles of 16 KiB
// (128 rows x 64 k); staging = 2 x gload16 per thread per half-tile.
// Swizzle both-sides: LDS dest linear; source k-slot = (t&7)^(row&7);
// frag read slot = (ks*4+fkc)^(row&7)  -> 2-way banks (free) on read+write.
// Per phase: {ds_read subtile; stage 1 half-tile; barrier; lgkmcnt(0)+
// sched_barrier; setprio(1) 16 MFMA setprio(0); barrier}.
// vmcnt ledger (2 loads/half-tile, lag-4 stage rotation):
//   P4: stage A0(even'); vmcnt(2) [guards P5-7 reads of odd tile]; barrier.
//   P8: stage A0(odd');  vmcnt(2) [guards next P1-3 reads of even tile].
//   Last iter P4: vmcnt(0) (no trailing stages to count against).
// vmcnt-BEFORE-barrier gives the cross-wave landing guarantee.
// 8 waves (2M x 4N), per-wave 128x64 output.
// EPI==0: C bf16 (ldc), coalesced via LDS half-passes.
// EPI==1: res = acc + X(bf16) + bias -> bf16 at Cv (ldc), LDS quarter-passes.
// ---------------------------------------------------------------------------
template<int EPI>
__global__ __launch_bounds__(512, 1) void gemm8x(const u16* __restrict__ A, int lda,
                                                 const u16* __restrict__ B,
                                                 u16* __restrict__ Cv, int ldc, int ntile,
                                                 const u16* __restrict__ Xb,
                                                 const float* __restrict__ bias)
{
    __shared__ __align__(16) u16 sm[65536];   // 128 KiB
    const int t    = threadIdx.x;
    const int lane = t & 63;
    const int w    = t >> 6;
    const int wm   = w >> 2;          // 0..1 -> A half
    const int wn   = w & 3;           // 0..3 -> B 64-col stripe

    // XCD-bijective blockIdx swizzle (nwg % 8 == 0 in all uses here)
    const int nwg  = gridDim.x;
    const int cpx  = nwg >> 3;
    const int bid  = blockIdx.x;
    const int sbid = (bid & 7) * cpx + (bid >> 3);
    const int mt = sbid / ntile, nt = sbid % ntile;
    const int rowBase = mt * 256, colBase = nt * 256;

    const int frow = lane & 15;
    const int fkc  = lane >> 4;       // 0..3
    const int orow = (lane >> 4) * 4;

    // staging geometry: thread t -> (r0 = t>>3 in 0..63, source k-slot)
    const int r0  = t >> 3;
    const int ksl = (t & 7) ^ (r0 & 7);

    f32x4 acc[8][4];
#pragma unroll
    for (int i = 0; i < 8; ++i)
#pragma unroll
        for (int j = 0; j < 4; ++j)
            acc[i][j] = (f32x4){0.f, 0.f, 0.f, 0.f};

    // stage half-tile L of matrix (A:reg=0 / B:reg=1), K-tile kt, into buf b
#define STG(Mp, ld_, base_, kt, L, b, reg)                                    \
    do {                                                                      \
        u16* d_ = &sm[(b) * 32768 + (reg) * 16384 + (L) * 8192];              \
        const u16* s_ = &Mp[(size_t)(base_ + (L) * 128 + r0) * (ld_)          \
                            + (kt) * 64 + ksl * 8];                           \
        gload16(s_, &d_[t * 8]);                                              \
        gload16(s_ + (size_t)64 * (ld_), &d_[4096 + t * 8]);                  \
    } while (0)
#define STG_A(kt, L, b) STG(A, lda, rowBase, kt, L, b, 0)
#define STG_B(kt, L, b) STG(B, HD, colBase, kt, L, b, 1)

    // frag reads: A 4 mm x 2 ks from wave's A-half; B 2 nn x 2 ks
#define FRD_A(dst, b, mm0)                                                    \
    do {                                                                      \
        const u16* h_ = &sm[(b) * 32768 + wm * 8192];                         \
        _Pragma("unroll")                                                     \
        for (int q_ = 0; q_ < 4; ++q_)                                        \
            _Pragma("unroll")                                                 \
            for (int ks_ = 0; ks_ < 2; ++ks_) {                               \
                const int row_ = ((mm0) + q_) * 16 + frow;                    \
                const int sl_ = (ks_ * 4 + fkc) ^ (row_ & 7);                 \
                dst[q_][ks_] = *reinterpret_cast<const bf16x8*>(              \
                    &h_[row_ * 64 + sl_ * 8]);                                \
            }                                                                 \
    } while (0)
#define FRD_B(dst, b, nn0)                                                    \
    do {                                                                      \
        const u16* h_ = &sm[(b) * 32768 + 16384 + (wn >> 1) * 8192];          \
        _Pragma("unroll")                                                     \
        for (int q_ = 0; q_ < 2; ++q_)                                        \
            _Pragma("unroll")                                                 \
            for (int ks_ = 0; ks_ < 2; ++ks_) {                               \
                const int row_ = (wn & 1) * 64 + ((nn0) + q_) * 16 + frow;    \
                const int sl_ = (ks_ * 4 + fkc) ^ (row_ & 7);                 \
                dst[q_][ks_] = *reinterpret_cast<const bf16x8*>(              \
                    &h_[row_ * 64 + sl_ * 8]);                                \
            }                                                                 \
    } while (0)
#define MFQ(m0, n0, aA, bA)                                                   \
    do {                                                                      \
        __builtin_amdgcn_s_setprio(1);                                        \
        _Pragma("unroll")                                                     \
        for (int mm_ = 0; mm_ < 4; ++mm_)                                     \
            _Pragma("unroll")                                                 \
            for (int nn_ = 0; nn_ < 2; ++nn_)                                 \
                _Pragma("unroll")                                             \
                for (int ks_ = 0; ks_ < 2; ++ks_)                             \
                    acc[(m0) + mm_][(n0) + nn_] =                             \
                        __builtin_amdgcn_mfma_f32_16x16x32_bf16(              \
                            aA[mm_][ks_], bA[nn_][ks_],                       \
                            acc[(m0) + mm_][(n0) + nn_], 0, 0, 0);            \
        __builtin_amdgcn_s_setprio(0);                                        \
    } while (0)
#define BARW()                                                                \
    do {                                                                      \
        __builtin_amdgcn_s_barrier();                                         \
        asm volatile("s_waitcnt lgkmcnt(0)" ::: "memory");                    \
        __builtin_amdgcn_sched_barrier(0);                                    \
    } while (0)
#define BAR() __builtin_amdgcn_s_barrier()

    // prologue: T0 full + T1-A0, then vmcnt(2)+barrier (T0 landed, all waves)
    STG_A(0, 0, 0); STG_A(0, 1, 0); STG_B(0, 0, 0); STG_B(0, 1, 0);
    STG_A(1, 0, 1);
    asm volatile("s_waitcnt vmcnt(2)" ::: "memory");
    BAR();

    bf16x8 aL[4][2], aH[4][2], bLo[2][2], bHi[2][2];

#pragma unroll 1
    for (int j = 0; j < 4; ++j) {
        const int te = 2 * j, to = 2 * j + 1;
        // ---- P1: even A-low + B-low ----
        FRD_A(aL, 0, 0); FRD_B(bLo, 0, 0);
        STG_A(to, 1, 1);
        BARW(); MFQ(0, 0, aL, bLo); BAR();
        // ---- P2: even B-high ----
        FRD_B(bHi, 0, 2);
        STG_B(to, 0, 1);
        BARW(); MFQ(0, 2, aL, bHi); BAR();
        // ---- P3: even A-high ----
        FRD_A(aH, 0, 4);
        STG_B(to, 1, 1);
        BARW(); MFQ(4, 0, aH, bLo); BAR();
        // ---- P4: reg-only; vmcnt guard for odd tile ----
        if (j < 3) {
            STG_A(te + 2, 0, 0);
            asm volatile("s_waitcnt vmcnt(2)" ::: "memory");
        } else {
            asm volatile("s_waitcnt vmcnt(0)" ::: "memory");
        }
        BAR(); MFQ(4, 2, aH, bHi); BAR();
        // ---- P5: odd A-low + B-low ----
        FRD_A(aL, 1, 0); FRD_B(bLo, 1, 0);
        if (j < 3) STG_A(te + 2, 1, 0);
        BARW(); MFQ(0, 0, aL, bLo); BAR();
        // ---- P6: odd B-high ----
        FRD_B(bHi, 1, 2);
        if (j < 3) STG_B(te + 2, 0, 0);
        BARW(); MFQ(0, 2, aL, bHi); BAR();
        // ---- P7: odd A-high ----
        FRD_A(aH, 1, 4);
        if (j < 3) STG_B(te + 2, 1, 0);
        BARW(); MFQ(4, 0, aH, bLo); BAR();
        // ---- P8: reg-only; vmcnt guard for next even tile ----
        if (j < 3) {
            STG_A(to + 2, 0, 1);
            asm volatile("s_waitcnt vmcnt(2)" ::: "memory");
        }
        BAR(); MFQ(4, 2, aH, bHi); BAR();
    }
#undef STG
#undef STG_A
#undef STG_B
#undef FRD_A
#undef FRD_B
#undef MFQ
#undef BARW
#undef BAR

    if (EPI == 0) {
        // two half-passes: 128x256 u16 = 64 KiB in LDS, coalesced ushort8 out
        u16* ldsC = sm;
#pragma unroll
        for (int hp = 0; hp < 2; ++hp) {
            __syncthreads();
            if (wm == hp) {
#pragma unroll
                for (int mm = 0; mm < 8; ++mm)
#pragma unroll
                    for (int nn = 0; nn < 4; ++nn) {
                        const int row0 = mm * 16 + orow;
                        const int col  = wn * 64 + nn * 16 + frow;
#pragma unroll
                        for (int r = 0; r < 4; ++r)
                            ldsC[(row0 + r) * 256 + col] = f2bf(acc[mm][nn][r]);
                    }
            }
            __syncthreads();
#pragma unroll
            for (int p = 0; p < 8; ++p) {
                const int lin = p * 512 + t;
                const int row = lin >> 5, c8 = lin & 31;
                *reinterpret_cast<ushort8*>(
                    &Cv[(size_t)(rowBase + hp * 128 + row) * ldc + colBase + c8 * 8]) =
                    *reinterpret_cast<const ushort8*>(&ldsC[row * 256 + c8 * 8]);
            }
        }
    } else {
        // four quarter-passes: 64x256 f32 = 64 KiB; res = acc + X + bias -> bf16
        float* ldsF = (float*)sm;
#pragma unroll
        for (int q = 0; q < 4; ++q) {
            __syncthreads();
            if (wm == (q >> 1)) {
#pragma unroll
                for (int mm = 0; mm < 4; ++mm) {
                    const int macc = (q & 1) * 4 + mm;
#pragma unroll
                    for (int nn = 0; nn < 4; ++nn) {
                        const int row0 = mm * 16 + orow;
                        const int col  = wn * 64 + nn * 16 + frow;
#pragma unroll
                        for (int r = 0; r < 4; ++r)
                            ldsF[(row0 + r) * 256 + col] = acc[macc][nn][r];
                    }
                }
            }
            __syncthreads();
#pragma unroll
            for (int p = 0; p < 8; ++p) {
                const int lin = p * 512 + t;
                const int row = lin >> 6, c4 = lin & 63;
                const int grow = rowBase + q * 64 + row;
                float4 a = *reinterpret_cast<const float4*>(&ldsF[row * 256 + c4 * 4]);
                ushort4v x4 = *reinterpret_cast<const ushort4v*>(
                    &Xb[(size_t)grow * HD + colBase + c4 * 4]);
                float4 b = *reinterpret_cast<const float4*>(&bias[colBase + c4 * 4]);
                ushort4v o;
                o[0] = f2bf(a.x + bf2f(x4[0]) + b.x);
                o[1] = f2bf(a.y + bf2f(x4[1]) + b.y);
                o[2] = f2bf(a.z + bf2f(x4[2]) + b.z);
                o[3] = f2bf(a.w + bf2f(x4[3]) + b.w);
                *reinterpret_cast<ushort4v*>(
                    &Cv[(size_t)grow * ldc + colBase + c4 * 4]) = o;
            }
        }
    }
}

// ---------------------------------------------------------------------------
// MFMA KtV: A[m,h,d,e] = sum_s k[m,s,d] * v[m,s,e]  (unchanged from R6)
// ---------------------------------------------------------------------------
__global__ __launch_bounds__(256) void kv_outer_mfma(const u16* __restrict__ qkv,
                                                     float* __restrict__ Abuf)
{
    __shared__ __align__(16) u16 kT[2048];
    __shared__ __align__(16) u16 vT[2048];
    const int t    = threadIdx.x;
    const int lane = t & 63;
    const int w    = t >> 6;
    const int hh   = blockIdx.x;
    const int m    = blockIdx.y;
    const int sl   = t & 31;
    const int dg   = (t >> 5) * 8;
    const int frow = lane & 15, fkc = lane >> 4, orow = (lane >> 4) * 4;
    const size_t gbase = (size_t)(m * S_SEG) * QKVLD + 512 + hh * DHEAD + dg;

    f32x4 acc[4];
#pragma unroll
    for (int i = 0; i < 4; ++i) acc[i] = (f32x4){0.f, 0.f, 0.f, 0.f};

    ushort8 ka, va, kb, vb;

#define LOADC(c, K8, V8)                                                      \
    do {                                                                      \
        size_t g_ = gbase + (size_t)((c) * 32 + sl) * QKVLD;                  \
        K8 = *reinterpret_cast<const ushort8*>(&qkv[g_]);                     \
        V8 = *reinterpret_cast<const ushort8*>(&qkv[g_ + 512]);               \
    } while (0)
#define WRTC(K8, V8)                                                          \
    do {                                                                      \
        _Pragma("unroll")                                                     \
        for (int j = 0; j < 8; ++j) {                                         \
            const int d_ = dg + j;                                            \
            const int a_ = d_ * 32 + ((((sl >> 3) ^ ((d_ >> 1) & 3))) << 3) + (sl & 7); \
            kT[a_] = K8[j];                                                   \
            vT[a_] = V8[j];                                                   \
        }                                                                     \
    } while (0)
#define CMPC()                                                                \
    do {                                                                      \
        bf16x8 kf[4], vf;                                                     \
        _Pragma("unroll")                                                     \
        for (int mf = 0; mf < 4; ++mf) {                                      \
            const int d_ = mf * 16 + frow;                                    \
            kf[mf] = *reinterpret_cast<const bf16x8*>(                        \
                &kT[d_ * 32 + ((fkc ^ ((d_ >> 1) & 3)) << 3)]);               \
        }                                                                     \
        const int e_ = w * 16 + frow;                                         \
        vf = *reinterpret_cast<const bf16x8*>(                                \
            &vT[e_ * 32 + ((fkc ^ ((e_ >> 1) & 3)) << 3)]);                   \
        _Pragma("unroll")                                                     \
        for (int mf = 0; mf < 4; ++mf)                                        \
            acc[mf] = __builtin_amdgcn_mfma_f32_16x16x32_bf16(kf[mf], vf, acc[mf], 0, 0, 0); \
    } while (0)

    LOADC(0, ka, va);
#pragma unroll 1
    for (int cc = 0; cc < 16; cc += 2) {
        WRTC(ka, va);
        LOADC(cc + 1, kb, vb);
        asm volatile("s_waitcnt lgkmcnt(0)" ::: "memory");
        __builtin_amdgcn_s_barrier();
        __builtin_amdgcn_sched_barrier(0);
        CMPC();
        __builtin_amdgcn_s_barrier();

        WRTC(kb, vb);
        if (cc + 2 < 16) LOADC(cc + 2, ka, va);
        asm volatile("s_waitcnt lgkmcnt(0)" ::: "memory");
        __builtin_amdgcn_s_barrier();
        __builtin_amdgcn_sched_barrier(0);
        CMPC();
        __builtin_amdgcn_s_barrier();
    }
#undef LOADC
#undef WRTC
#undef CMPC

    const size_t hb = (size_t)(m * NHEAD + hh) * DHEAD * DHEAD;
#pragma unroll
    for (int mf = 0; mf < 4; ++mf)
#pragma unroll
        for (int r = 0; r < 4; ++r)
            Abuf[hb + (size_t)(mf * 16 + orow + r) * DHEAD + w * 16 + frow] = acc[mf][r];
}

// ---------------------------------------------------------------------------
// r_m = A_m + decay*r_{m-1} ;  Bc_m = scale*A_m + gamma^{m+1} * r_m  (fp32)
// ---------------------------------------------------------------------------
__global__ __launch_bounds__(256) void scan_kernel(const float* __restrict__ Abuf,
                                                   float* __restrict__ Bc)
{
    const int tid = blockIdx.x * 256 + threadIdx.x;   // 0..32767
    const float decay = powf(GAMMA_F, (float)S_SEG);
    float r = 0.0f;
    float g = 1.0f;
    for (int m = 0; m < M_SEG; ++m) {
        float a = Abuf[(size_t)m * 32768 + tid];
        r = fmaf(decay, r, a);
        g *= GAMMA_F;
        Bc[(size_t)m * 32768 + tid] = fmaf(g, r, SCALE_F * a);
    }
}

// ---------------------------------------------------------------------------
// h = relu(q @ Bc) written IN PLACE into qkv's q-slot  (R5-proven)
// ---------------------------------------------------------------------------
__global__ __launch_bounds__(256) void h_mfma(u16* __restrict__ qkv,
                                              const float* __restrict__ Bc)
{
    __shared__ __align__(16) u16 BT[64 * 72];    // Bc^T [e][d], pad 72
    const int t    = threadIdx.x;
    const int lane = t & 63;
    const int w    = t >> 6;
    const int m    = blockIdx.y;
    const int sBase = blockIdx.x * 256 + w * 64;
    const int frow = lane & 15;
    const int fkc  = lane >> 4;

    for (int hh = 0; hh < NHEAD; ++hh) {
#pragma unroll
        for (int i = 0; i < 4; ++i) {
            int idx = t + i * 256;               // 1024 float4s
            int d = idx >> 4, e4 = idx & 15;
            float4 v = *reinterpret_cast<const float4*>(
                &Bc[((size_t)(m * NHEAD + hh) * DHEAD + d) * DHEAD + e4 * 4]);
            BT[(e4 * 4 + 0) * 72 + d] = f2bf(v.x);
            BT[(e4 * 4 + 1) * 72 + d] = f2bf(v.y);
            BT[(e4 * 4 + 2) * 72 + d] = f2bf(v.z);
            BT[(e4 * 4 + 3) * 72 + d] = f2bf(v.w);
        }
        __syncthreads();

        f32x4 acc[4][4];
#pragma unroll
        for (int i = 0; i < 4; ++i)
#pragma unroll
            for (int j = 0; j < 4; ++j)
                acc[i][j] = (f32x4){0.f, 0.f, 0.f, 0.f};

#pragma unroll
        for (int ks = 0; ks < 2; ++ks) {
            bf16x8 af[4], bfr[4];
#pragma unroll
            for (int mm = 0; mm < 4; ++mm) {
                const int grow = m * S_SEG + sBase + mm * 16 + frow;
                af[mm] = *reinterpret_cast<const bf16x8*>(
                    &qkv[(size_t)grow * QKVLD + hh * DHEAD + ks * 32 + fkc * 8]);
                const int e = mm * 16 + frow;
                bfr[mm] = *reinterpret_cast<const bf16x8*>(&BT[e * 72 + ks * 32 + fkc * 8]);
            }
#pragma unroll
            for (int mm = 0; mm < 4; ++mm)
#pragma unroll
                for (int nn = 0; nn < 4; ++nn)
                    acc[mm][nn] = __builtin_amdgcn_mfma_f32_16x16x32_bf16(af[mm], bfr[nn], acc[mm][nn], 0, 0, 0);
        }

        const int orow = (lane >> 4) * 4;
#pragma unroll
        for (int mm = 0; mm < 4; ++mm)
#pragma unroll
            for (int nn = 0; nn < 4; ++nn) {
                const int col  = hh * DHEAD + nn * 16 + frow;
                const int row0 = m * S_SEG + sBase + mm * 16 + orow;
#pragma unroll
                for (int r = 0; r < 4; ++r)
                    qkv[(size_t)(row0 + r) * QKVLD + col] = f2bf(fmaxf(acc[mm][nn][r], 0.f));
            }
        __syncthreads();
    }
}

// ---------------------------------------------------------------------------
// GroupNorm from bf16 res (qkv k-slot, stride 1536) -> fp32 d_out rows 1..N
// ---------------------------------------------------------------------------
__global__ __launch_bounds__(256) void groupnorm_bf16(const u16* __restrict__ res,
                                                      float* __restrict__ out,
                                                      const float* __restrict__ gn_w,
                                                      const float* __restrict__ gn_b)
{
    const int g = blockIdx.x;
    const int m = blockIdx.y;
    const int t = threadIdx.x;
    const u16* base = res + (size_t)(m * S_SEG) * QKVLD + g * DHEAD;

    float sum = 0.0f, sq = 0.0f;
    for (int idx = t; idx < 4096; idx += 256) {      // 512 rows x 8 ushort8
        int s = idx >> 3, c8 = idx & 7;
        ushort8 v = *reinterpret_cast<const ushort8*>(&base[(size_t)s * QKVLD + c8 * 8]);
#pragma unroll
        for (int j = 0; j < 8; ++j) {
            float f = bf2f(v[j]);
            sum += f; sq += f * f;
        }
    }
    __shared__ float rs[256], rq[256];
    rs[t] = sum; rq[t] = sq;
    __syncthreads();
    for (int off = 128; off > 0; off >>= 1) {
        if (t < off) { rs[t] += rs[t + off]; rq[t] += rq[t + off]; }
        __syncthreads();
    }
    __shared__ float smean, sinv;
    if (t == 0) {
        float mean = rs[0] * (1.0f / 32768.0f);
        float var  = rq[0] * (1.0f / 32768.0f) - mean * mean;
        smean = mean;
        sinv  = rsqrtf(var + 1e-5f);
    }
    __syncthreads();
    const float mean = smean, inv = sinv;

    for (int idx = t; idx < 4096; idx += 256) {
        int s = idx >> 3, c8 = idx & 7;
        ushort8 v = *reinterpret_cast<const ushort8*>(&base[(size_t)s * QKVLD + c8 * 8]);
        float o[8];
#pragma unroll
        for (int j = 0; j < 8; ++j) {
            float wj = gn_w[g * DHEAD + c8 * 8 + j];
            float bj = gn_b[g * DHEAD + c8 * 8 + j];
            o[j] = (bf2f(v[j]) - mean) * inv * wj + bj;
        }
        float* dst = &out[(size_t)(1 + m * S_SEG + s) * HD + g * DHEAD + c8 * 8];
        *reinterpret_cast<float4*>(dst)     = make_float4(o[0], o[1], o[2], o[3]);
        *reinterpret_cast<float4*>(dst + 4) = make_float4(o[4], o[5], o[6], o[7]);
    }
}

__global__ void zero_row(float* __restrict__ out)
{
    int i = blockIdx.x * 256 + threadIdx.x;
    if (i < HD) out[i] = 0.0f;
}

// ---------------------------------------------------------------------------
extern "C" void kernel_launch(void* const* d_in, const int* in_sizes, int n_in,
                              void* d_out, int out_size, void* d_ws, size_t ws_size,
                              hipStream_t stream)
{
    const float* msg = (const float*)d_in[0];
    const float* Wq  = (const float*)d_in[1];
    const float* Wk  = (const float*)d_in[2];
    const float* Wv  = (const float*)d_in[3];
    const float* Wo  = (const float*)d_in[4];
    const float* bo  = (const float*)d_in[5];
    const float* gnw = (const float*)d_in[6];
    const float* gnb = (const float*)d_in[7];
    float* out = (float*)d_out;

    // d_out scratch (consumed before groupnorm rewrites d_out):
    //   msgb bf16 (67.1 MB) | Abuf fp32 (16.8 MB) | Bc fp32 (16.8 MB)
    u16*   msgb = (u16*)out;
    float* Abuf = out + 16777216;
    float* Bc   = out + 16777216 + 4194304;

    // d_ws: Wb 2 MB (Wq|Wk|Wv|Wo bf16) + qkv 201.3 MB (65536 x 1536).
    // h_mfma overwrites qkv's q-slot with h; EPI gemm writes bf16 res into
    // qkv's k-slot (dead after kv_outer_mfma).
    u16* Wb   = (u16*)d_ws;
    u16* qkv  = Wb + 4 * 262144;
    u16* resB = qkv + 512;    // res bf16, stride 1536

    convert_weights<<<dim3(128, 4), 256, 0, stream>>>(Wq, Wk, Wv, Wo, Wb);
    convert_bf16<<<16384, 256, 0, stream>>>(msg, msgb, 4194304);

    // fused QKV GEMM: A=msgb (65536x512), B=[Wq;Wk;Wv] (1536x512) -> qkv
    gemm8x<0><<<1536, 512, 0, stream>>>(msgb, HD, Wb, qkv, QKVLD, 6, nullptr, nullptr);

    kv_outer_mfma<<<dim3(NHEAD, M_SEG), 256, 0, stream>>>(qkv, Abuf);
    scan_kernel<<<128, 256, 0, stream>>>(Abuf, Bc);
    h_mfma<<<dim3(2, M_SEG), 256, 0, stream>>>(qkv, Bc);

    // output GEMM: A=h (qkv q-slot, lda=1536), B=Wo; res=acc+msgb+bias -> bf16
    gemm8x<1><<<512, 512, 0, stream>>>(qkv, QKVLD, Wb + 3 * 262144, resB, QKVLD, 2, msgb, bo);

    zero_row<<<2, 256, 0, stream>>>(out);
    groupnorm_bf16<<<dim3(8, M_SEG), 256, 0, stream>>>(resB, out, gnw, gnb);
}